// Round 2
// baseline (167.687 us; speedup 1.0000x reference)
//
#include <hip/hip_runtime.h>
#include <math.h>
#include <stdint.h>

#define Bsz 4096
#define Ssz 200
#define Dsz 64
#define NK  5
#define NT  512

typedef _Float16 half_t;
typedef _Float16 h2    __attribute__((ext_vector_type(2)));
typedef _Float16 f16x8 __attribute__((ext_vector_type(8)));
typedef float    f32x4 __attribute__((ext_vector_type(4)));

#define RSTRIDE 72    // embR row stride in halves (144 B)
#define TSTRIDE 232   // embT row stride in halves (464 B)

__device__ inline h2 pk(float a, float b) {
    return __builtin_bit_cast(h2, __builtin_amdgcn_cvt_pkrtz(a, b));
}

__device__ inline float fast_tanh(float x) {
    float e = __expf(-2.0f * fabsf(x));
    float r = (1.0f - e) / (1.0f + e);
    return copysignf(r, x);
}

__global__ void zero_loss_kernel(float* loss) {
    if (threadIdx.x == 0) *loss = 0.0f;
}

__global__ __launch_bounds__(NT, 4) void tan_kernel(
    const int* __restrict__ x, const float* __restrict__ y,
    const float* __restrict__ emb_table,
    const float* __restrict__ att_w, const float* __restrict__ att_b,
    const float* __restrict__ W0, const float* __restrict__ W1,
    const float* __restrict__ W2, const float* __restrict__ W3,
    const float* __restrict__ W4,
    float* __restrict__ out_logit, float* __restrict__ loss_out)
{
    // Two fp16 copies of the gathered embeddings (MFMA operands are
    // k-contiguous per lane; logits contract over d, user_rep over s):
    __shared__ alignas(16) half_t embR[208 * RSTRIDE]; // 29952 B row-major [s][d]
    __shared__ alignas(16) half_t embT[64 * TSTRIDE];  // 29696 B transposed [d][s]
    __shared__ alignas(16) float  ovl[1000];           //  4000 B att_raw[5][200] | urp[2][5][64]+ur
    __shared__ alignas(16) half_t ascore[NK * 240];    //  2400 B score[k][s], K-tail zeroed
    __shared__ alignas(16) half_t awh[NK * RSTRIDE];   //   720 B att_w fp16
    __shared__ alignas(16) int    xs[Ssz];             //   800 B
    __shared__ float wu[18];                           //    72 B
    // total ~67.6 KB -> 2 blocks/CU (16 waves/CU; measured occupancy was ~17)

    float* att_raw = ovl;   // [5][200] fp32, dead after P2

    const int b   = blockIdx.x;
    const int tid = threadIdx.x;
    const int w   = tid >> 6;
    const int l   = tid & 63;
    const int col = l & 15;       // MFMA minor index
    const int kg  = l >> 4;       // MFMA k-group (k = 8*kg + j)

    // ---- P0: stage x; zero embR rows 200..207 and embT cols 200..223; att_w->h2 ----
    if (tid < Ssz) xs[tid] = x[b * Ssz + tid];
    {
        uint4 z = {0u, 0u, 0u, 0u};
        if (tid < 72)   // embR rows 200..207 = 8*144 B = 72 uint4
            *(uint4*)((char*)embR + 200 * 144 + tid * 16) = z;
        if (tid >= 72 && tid < 72 + 192) {  // embT[d][200..223] = 48 B x 64 rows
            const int idx = tid - 72, row = idx / 3, q = idx - row * 3;
            *(uint4*)((char*)embT + row * 464 + 400 + q * 16) = z;
        }
    }
    if (tid >= 256 && tid < 256 + NK * 32) {
        const int t = tid - 256, row = t >> 5, cp = t & 31;
        h2 v = {(half_t)att_w[row * 64 + 2 * cp],
                (half_t)att_w[row * 64 + 2 * cp + 1]};
        *(h2*)(awh + row * RSTRIDE + 2 * cp) = v;
    }
    __syncthreads();

    // ---- P1: coalesced gather, 16 lanes/row; write embR (uint2) + embT (scatter) ----
    {
        float4 v[7];
#pragma unroll
        for (int p = 0; p < 7; ++p) {
            int i = tid + NT * p;
            if (i > Ssz * 16 - 1) i = Ssz * 16 - 1;
            const int s = i >> 4, c = i & 15;
            v[p] = ((const float4*)(emb_table + (size_t)xs[s] * Dsz))[c];
        }
#pragma unroll
        for (int p = 0; p < 7; ++p) {
            const int i = tid + NT * p;
            if (p < 6 || i < Ssz * 16) {
                const int s = i >> 4, c = i & 15;
                h2 lo = pk(v[p].x, v[p].y);
                h2 hi = pk(v[p].z, v[p].w);
                uint2 u = { __builtin_bit_cast(unsigned, lo),
                            __builtin_bit_cast(unsigned, hi) };
                *(uint2*)(embR + s * RSTRIDE + c * 4) = u;
                embT[(4 * c + 0) * TSTRIDE + s] = lo.x;
                embT[(4 * c + 1) * TSTRIDE + s] = lo.y;
                embT[(4 * c + 2) * TSTRIDE + s] = hi.x;
                embT[(4 * c + 3) * TSTRIDE + s] = hi.y;
            }
        }
    }
    __syncthreads();

    // ---- P1.5: attention logits via MFMA: C[s][attr] = emb(16x64) . aw^T(64x5) ----
    // A: lane holds emb[16t+col][kg*8+j]; B: aw[col(clamped)][kg*8+j].
    // C: col=attr (cols 5..15 garbage, ignored), row=(l>>4)*4+r = s-local.
    {
        const int brow = (col < 5) ? col : 0;
        const f16x8 bw0 = *(const f16x8*)(awh + brow * RSTRIDE + kg * 8);
        const f16x8 bw1 = *(const f16x8*)(awh + brow * RSTRIDE + 32 + kg * 8);
        const float bk = att_b[brow];   // clamped index: no OOB speculation
        for (int t = w; t < 13; t += 8) {        // 13 s-tiles of 16
            const int s = 16 * t + col;
            const f16x8 a0 = *(const f16x8*)(embR + s * RSTRIDE + kg * 8);
            const f16x8 a1 = *(const f16x8*)(embR + s * RSTRIDE + 32 + kg * 8);
            f32x4 acc = {0.f, 0.f, 0.f, 0.f};
            acc = __builtin_amdgcn_mfma_f32_16x16x32_f16(a0, bw0, acc, 0, 0, 0);
            acc = __builtin_amdgcn_mfma_f32_16x16x32_f16(a1, bw1, acc, 0, 0, 0);
            if (col < 5) {
#pragma unroll
                for (int r = 0; r < 4; ++r) {
                    const int srow = 16 * t + 4 * kg + r;
                    if (srow < Ssz)
                        att_raw[col * 200 + srow] = fast_tanh(acc[r] + bk);
                }
            }
        }
    }
    __syncthreads();

    // ---- P2: softmax over s per k (waves 0..4) -> fp16 A/B operand, zero K-tail ----
    if (w < NK) {
        const int k = w;
        float vals[4];
        float mx = -1e30f;
#pragma unroll
        for (int j = 0; j < 4; ++j) {
            const int s = l + 64 * j;
            vals[j] = (s < Ssz) ? att_raw[k * 200 + s] : -1e30f;
            mx = fmaxf(mx, vals[j]);
        }
#pragma unroll
        for (int m = 32; m >= 1; m >>= 1) mx = fmaxf(mx, __shfl_xor(mx, m));
        float sum = 0.f;
#pragma unroll
        for (int j = 0; j < 4; ++j) {
            vals[j] = __expf(vals[j] - mx);
            sum += vals[j];
        }
#pragma unroll
        for (int m = 32; m >= 1; m >>= 1) sum += __shfl_xor(sum, m);
        const float inv = 1.0f / sum;
#pragma unroll
        for (int j = 0; j < 4; ++j) {
            const int s = l + 64 * j;
            if (s < Ssz)      ascore[k * 240 + s] = (half_t)(vals[j] * inv);
            else if (s < 224) ascore[k * 240 + s] = (half_t)0.0f;  // MFMA K-tail
        }
    }
    __syncthreads();   // att_raw dead; ovl becomes urp/ur

    // ---- P3: user_rep via MFMA, output flipped: C[d][attr] = embT(16x224).score^T(224x5)
    // wave w: dtile = w&3 (16 d-rows), K-half = w>>2 (kk 0..3 / 4..6).
    // A: lane holds embT[dtile*16+col][kk*32+kg*8+j]   (s-contiguous b128)
    // B: lane holds score[col(clamped)][kk*32+kg*8+j]  (b128; cols 5..15 garbage)
    // C: col=attr, row=(l>>4)*4+r = d-local.
    {
        const int dtile = w & 3, hh = w >> 2;
        const int arow = (col < 5) ? col : 0;
        const int KK0 = hh ? 4 : 0;
        const int NKK = hh ? 3 : 4;
        f32x4 acc = {0.f, 0.f, 0.f, 0.f};
        for (int q = 0; q < NKK; ++q) {     // wave-uniform bound
            const int kk = KK0 + q;
            const f16x8 af = *(const f16x8*)(embT + (dtile * 16 + col) * TSTRIDE
                                             + kk * 32 + kg * 8);
            const f16x8 bf = *(const f16x8*)(ascore + arow * 240 + kk * 32 + kg * 8);
            acc = __builtin_amdgcn_mfma_f32_16x16x32_f16(af, bf, acc, 0, 0, 0);
        }
        float* urp = ovl + hh * 320;        // partial ur[attr][d]
        if (col < 5) {
#pragma unroll
            for (int r = 0; r < 4; ++r)
                urp[col * 64 + dtile * 16 + 4 * kg + r] = acc[r];
        }
    }
    __syncthreads();

    // ---- P4: fold the two K-half partials -> ur fp32 at ovl+640 ----
    if (tid < NK * Dsz) ovl[640 + tid] = ovl[tid] + ovl[320 + tid];
    __syncthreads();

    // ---- P5: W_user[j] = ur[g(j)] . W_g[r(j)] ----
    for (int j = w; j < 18; j += 8) {
        const float* Wp; int gr, c0;
        if      (j < 2)  { gr = 0; c0 = 0;  Wp = W0; }
        else if (j < 6)  { gr = 1; c0 = 2;  Wp = W1; }
        else if (j < 10) { gr = 2; c0 = 6;  Wp = W2; }
        else if (j < 12) { gr = 3; c0 = 10; Wp = W3; }
        else             { gr = 4; c0 = 12; Wp = W4; }
        float p = ovl[640 + gr * 64 + l] * Wp[(j - c0) * Dsz + l];
#pragma unroll
        for (int m = 32; m >= 1; m >>= 1) p += __shfl_xor(p, m);
        if (l == 0) wu[j] = p;
    }
    __syncthreads();

    // ---- P6: per-group softmax -> logits; CE -> atomic loss ----
    if (w == 0) {
        float lossb = 0.f;
        if (l < NK) {
            const int LEN[5] = {2, 4, 4, 2, 6};
            const int C0[5]  = {0, 2, 6, 10, 12};
            const int gidx = l, c0 = C0[gidx], len = LEN[gidx];
            float* op = out_logit + (size_t)b * 18;
            const float* yp = y + (size_t)b * 18;
            float mx = -1e30f;
            for (int j = 0; j < len; ++j) mx = fmaxf(mx, wu[c0 + j]);
            float sum = 0.f;
            for (int j = 0; j < len; ++j) sum += __expf(wu[c0 + j] - mx);
            float inv = 1.0f / sum;
            float lse = mx + __logf(sum);
            for (int j = 0; j < len; ++j) {
                op[c0 + j] = __expf(wu[c0 + j] - mx) * inv;
                lossb += (lse - wu[c0 + j]) * yp[c0 + j];
            }
        }
#pragma unroll
        for (int m = 1; m <= 4; m <<= 1) lossb += __shfl_xor(lossb, m);
        if (l == 0) atomicAdd(loss_out, lossb * (1.0f / Bsz));
    }
}

extern "C" void kernel_launch(void* const* d_in, const int* in_sizes, int n_in,
                              void* d_out, int out_size, void* d_ws, size_t ws_size,
                              hipStream_t stream) {
    const int*   x   = (const int*)d_in[0];
    const float* y   = (const float*)d_in[1];
    const float* emb = (const float*)d_in[2];
    const float* aw  = (const float*)d_in[3];
    const float* ab  = (const float*)d_in[4];
    const float* W0  = (const float*)d_in[5];
    const float* W1  = (const float*)d_in[6];
    const float* W2  = (const float*)d_in[7];
    const float* W3  = (const float*)d_in[8];
    const float* W4  = (const float*)d_in[9];
    float* out  = (float*)d_out;
    float* loss = out + (size_t)Bsz * 18;

    zero_loss_kernel<<<1, 64, 0, stream>>>(loss);
    tan_kernel<<<Bsz, NT, 0, stream>>>(x, y, emb, aw, ab,
                                       W0, W1, W2, W3, W4, out, loss);
}

// Round 3
// 157.358 us; speedup vs baseline: 1.0656x; 1.0656x over previous
//
#include <hip/hip_runtime.h>
#include <math.h>
#include <stdint.h>

#define Bsz 4096
#define Ssz 200
#define Dsz 64
#define NK  5
#define NT  512
#define RST 72      // embR row stride in halves (144 B)
#define TST 232     // embT row stride in halves (464 B)
#define UNIH 14848  // union size in halves (29696 B) = embT size >= embR (200*72)

typedef _Float16 half_t;
typedef _Float16 h2    __attribute__((ext_vector_type(2)));
typedef _Float16 f16x8 __attribute__((ext_vector_type(8)));
typedef float    f32x4 __attribute__((ext_vector_type(4)));

__device__ inline h2 pk(float a, float b) {
    return __builtin_bit_cast(h2, __builtin_amdgcn_cvt_pkrtz(a, b));
}

__device__ inline float fast_tanh(float x) {
    float e = __expf(-2.0f * fabsf(x));
    float r = (1.0f - e) / (1.0f + e);
    return copysignf(r, x);
}

__global__ void zero_loss_kernel(float* loss) {
    if (threadIdx.x == 0) *loss = 0.0f;
}

// fp32 table -> fp16 table in workspace (streaming, ~6 us)
__global__ __launch_bounds__(256) void cvt_kernel(const float* __restrict__ src,
                                                  half_t* __restrict__ dst) {
    const size_t i = ((size_t)blockIdx.x * 256 + threadIdx.x) * 8;
    if (i < (size_t)100000 * 64) {
        float4 v0 = *(const float4*)(src + i);
        float4 v1 = *(const float4*)(src + i + 4);
        union { half_t h[8]; uint4 u; } o;
        o.h[0] = (half_t)v0.x; o.h[1] = (half_t)v0.y;
        o.h[2] = (half_t)v0.z; o.h[3] = (half_t)v0.w;
        o.h[4] = (half_t)v1.x; o.h[5] = (half_t)v1.y;
        o.h[6] = (half_t)v1.z; o.h[7] = (half_t)v1.w;
        *(uint4*)(dst + i) = o.u;
    }
}

template <bool F16TAB>
__global__ __launch_bounds__(NT, 8) void tan_kernel(
    const int* __restrict__ x, const float* __restrict__ y,
    const float* __restrict__ emb_table, const half_t* __restrict__ tab16,
    const float* __restrict__ att_w, const float* __restrict__ att_b,
    const float* __restrict__ W0, const float* __restrict__ W1,
    const float* __restrict__ W2, const float* __restrict__ W3,
    const float* __restrict__ W4,
    float* __restrict__ out_logit, float* __restrict__ loss_out)
{
    // One union buffer, time-multiplexed:
    //   embR [200][RST] fp16 row-major  (P1..P1.5, transpose source)
    //   embT [64][TST]  fp16 transposed (P2 writes, P3 reads) -- same bytes
    __shared__ alignas(16) half_t uni[UNIH];           // 29696 B
    __shared__ alignas(16) float  ovl[1000];           //  4000 B att_raw[5][200] | urp+ur
    __shared__ alignas(16) half_t ascore[NK * 240];    //  2400 B score[k][s], K-tail zeroed
    __shared__ alignas(16) half_t awh[NK * RST];       //   720 B att_w fp16
    __shared__ alignas(16) int    xs[Ssz];             //   800 B
    __shared__ float wu[18];                           //    72 B
    // total ~37.7 KB -> 4 blocks/CU -> 32 waves/CU

    half_t* embR = uni;
    half_t* embT = uni;
    float*  att_raw = ovl;   // [5][200] fp32, dead after P2

    const int b   = blockIdx.x;
    const int tid = threadIdx.x;
    const int w   = tid >> 6;
    const int l   = tid & 63;
    const int col = l & 15;       // MFMA minor index
    const int kg  = l >> 4;       // MFMA k-group (k = 8*kg + j)

    // ---- P0: stage x; zero embT s-tail cols 200..223; att_w -> fp16 ----
    // (tail zeros at bytes >= 28800 survive P1; lower rows get overwritten by
    //  embR with finite fp16 which is safe: tail is multiplied by score==0)
    if (tid < Ssz) xs[tid] = x[b * Ssz + tid];
    if (tid < 192) {   // embT[d][200..223] = 48 B x 64 rows
        const int row = tid / 3, q = tid - row * 3;
        uint4 z = {0u, 0u, 0u, 0u};
        *(uint4*)((char*)embT + row * 464 + 400 + q * 16) = z;
    }
    if (tid >= 256 && tid < 256 + NK * 32) {
        const int t = tid - 256, row = t >> 5, cp = t & 31;
        h2 v = {(half_t)att_w[row * 64 + 2 * cp],
                (half_t)att_w[row * 64 + 2 * cp + 1]};
        *(h2*)(awh + row * RST + 2 * cp) = v;
    }
    __syncthreads();

    // ---- P1: coalesced gather -> embR ----
    if (F16TAB) {
        // fp16 table: 8 lanes/row, 16 B each; 1600 chunk loads/block
        uint4 g[4];
#pragma unroll
        for (int p = 0; p < 4; ++p) {
            int i = tid + NT * p;
            if (i > 1599) i = 1599;
            const int s = i >> 3, c = i & 7;
            g[p] = *(const uint4*)(tab16 + (size_t)xs[s] * Dsz + c * 8);
        }
#pragma unroll
        for (int p = 0; p < 4; ++p) {
            const int i = tid + NT * p;
            if (p < 3 || i < 1600) {
                const int s = i >> 3, c = i & 7;
                *(uint4*)(embR + s * RST + c * 8) = g[p];
            }
        }
    } else {
        // fp32 table fallback: 16 lanes/row, convert in-flight
        float4 v[7];
#pragma unroll
        for (int p = 0; p < 7; ++p) {
            int i = tid + NT * p;
            if (i > Ssz * 16 - 1) i = Ssz * 16 - 1;
            const int s = i >> 4, c = i & 15;
            v[p] = ((const float4*)(emb_table + (size_t)xs[s] * Dsz))[c];
        }
#pragma unroll
        for (int p = 0; p < 7; ++p) {
            const int i = tid + NT * p;
            if (p < 6 || i < Ssz * 16) {
                const int s = i >> 4, c = i & 15;
                h2 lo = pk(v[p].x, v[p].y);
                h2 hi = pk(v[p].z, v[p].w);
                uint2 u = { __builtin_bit_cast(unsigned, lo),
                            __builtin_bit_cast(unsigned, hi) };
                *(uint2*)(embR + s * RST + c * 4) = u;
            }
        }
    }
    __syncthreads();

    // ---- transpose READS (all threads; overlap with P1.5 MFMA) ----
    // task t: dp = t&31 (d-pair 2dp,2dp+1), sq = t>>5 (s-quad 4sq..4sq+3)
    h2 te[4][4];
#pragma unroll
    for (int p = 0; p < 4; ++p) {
        int t = tid + NT * p;
        if (t > 1599) t = 1599;
        const int dp = t & 31, sq = t >> 5;
#pragma unroll
        for (int r = 0; r < 4; ++r)
            te[p][r] = *(const h2*)(embR + (4 * sq + r) * RST + 2 * dp);
    }

    // ---- P1.5: attention logits via MFMA: C[s][attr] = emb(16x64) . aw^T ----
    // A rows clamp to 199 for the s-tail (garbage C rows discarded).
    {
        const int brow = (col < 5) ? col : 0;
        const f16x8 bw0 = *(const f16x8*)(awh + brow * RST + kg * 8);
        const f16x8 bw1 = *(const f16x8*)(awh + brow * RST + 32 + kg * 8);
        const float bk = att_b[brow];
        for (int t = w; t < 13; t += 8) {        // 13 s-tiles of 16
            const int s  = 16 * t + col;
            const int sr = (s < Ssz) ? s : (Ssz - 1);
            const f16x8 a0 = *(const f16x8*)(embR + sr * RST + kg * 8);
            const f16x8 a1 = *(const f16x8*)(embR + sr * RST + 32 + kg * 8);
            f32x4 acc = {0.f, 0.f, 0.f, 0.f};
            acc = __builtin_amdgcn_mfma_f32_16x16x32_f16(a0, bw0, acc, 0, 0, 0);
            acc = __builtin_amdgcn_mfma_f32_16x16x32_f16(a1, bw1, acc, 0, 0, 0);
            if (col < 5) {                       // C: col=attr, row=4kg+r=s-local
#pragma unroll
                for (int r = 0; r < 4; ++r) {
                    const int srow = 16 * t + 4 * kg + r;
                    if (srow < Ssz)
                        att_raw[col * 200 + srow] = fast_tanh(acc[r] + bk);
                }
            }
        }
    }
    __syncthreads();   // embR reads (incl. transpose reads) all complete

    // ---- P2: transpose WRITES (all threads) || softmax (waves 0..4) ----
#pragma unroll
    for (int p = 0; p < 4; ++p) {
        const int t = tid + NT * p;
        if (t < 1600) {
            const int dp = t & 31, sq = t >> 5;
            h2 lo01 = {te[p][0].x, te[p][1].x}, lo23 = {te[p][2].x, te[p][3].x};
            h2 hi01 = {te[p][0].y, te[p][1].y}, hi23 = {te[p][2].y, te[p][3].y};
            uint2 ulo = { __builtin_bit_cast(unsigned, lo01),
                          __builtin_bit_cast(unsigned, lo23) };
            uint2 uhi = { __builtin_bit_cast(unsigned, hi01),
                          __builtin_bit_cast(unsigned, hi23) };
            *(uint2*)(embT + (2 * dp)     * TST + 4 * sq) = ulo;
            *(uint2*)(embT + (2 * dp + 1) * TST + 4 * sq) = uhi;
        }
    }
    if (w < NK) {
        const int k = w;
        float vals[4];
        float mx = -1e30f;
#pragma unroll
        for (int j = 0; j < 4; ++j) {
            const int s = l + 64 * j;
            vals[j] = (s < Ssz) ? att_raw[k * 200 + s] : -1e30f;
            mx = fmaxf(mx, vals[j]);
        }
#pragma unroll
        for (int m = 32; m >= 1; m >>= 1) mx = fmaxf(mx, __shfl_xor(mx, m));
        float sum = 0.f;
#pragma unroll
        for (int j = 0; j < 4; ++j) {
            vals[j] = __expf(vals[j] - mx);
            sum += vals[j];
        }
#pragma unroll
        for (int m = 32; m >= 1; m >>= 1) sum += __shfl_xor(sum, m);
        const float inv = 1.0f / sum;
#pragma unroll
        for (int j = 0; j < 4; ++j) {
            const int s = l + 64 * j;
            if (s < Ssz)      ascore[k * 240 + s] = (half_t)(vals[j] * inv);
            else if (s < 224) ascore[k * 240 + s] = (half_t)0.0f;  // MFMA K-tail
        }
    }
    __syncthreads();   // embT + ascore ready; att_raw dead -> ovl becomes urp

    // ---- P3: user_rep via MFMA: C[d][attr] = embT(16x224) . score^T(224x5) ----
    // wave w: dtile = w&3 (16 d-rows), K-half = w>>2 (kk 0..3 / 4..6)
    {
        const int dtile = w & 3, hh = w >> 2;
        const int arow = (col < 5) ? col : 0;
        const int KK0 = hh ? 4 : 0;
        const int NKK = hh ? 3 : 4;
        f32x4 acc = {0.f, 0.f, 0.f, 0.f};
        for (int q = 0; q < NKK; ++q) {     // wave-uniform bound
            const int kk = KK0 + q;
            const f16x8 af = *(const f16x8*)(embT + (dtile * 16 + col) * TST
                                             + kk * 32 + kg * 8);
            const f16x8 bf = *(const f16x8*)(ascore + arow * 240 + kk * 32 + kg * 8);
            acc = __builtin_amdgcn_mfma_f32_16x16x32_f16(af, bf, acc, 0, 0, 0);
        }
        float* urp = ovl + hh * 320;        // partial ur[attr][d]
        if (col < 5) {
#pragma unroll
            for (int r = 0; r < 4; ++r)
                urp[col * 64 + dtile * 16 + 4 * kg + r] = acc[r];
        }
    }
    __syncthreads();

    // ---- P4: fold the two K-half partials -> ur fp32 at ovl+640 ----
    if (tid < NK * Dsz) ovl[640 + tid] = ovl[tid] + ovl[320 + tid];
    __syncthreads();

    // ---- P5: W_user[j] = ur[g(j)] . W_g[r(j)] ----
    for (int j = w; j < 18; j += 8) {
        const float* Wp; int gr, c0;
        if      (j < 2)  { gr = 0; c0 = 0;  Wp = W0; }
        else if (j < 6)  { gr = 1; c0 = 2;  Wp = W1; }
        else if (j < 10) { gr = 2; c0 = 6;  Wp = W2; }
        else if (j < 12) { gr = 3; c0 = 10; Wp = W3; }
        else             { gr = 4; c0 = 12; Wp = W4; }
        float p = ovl[640 + gr * 64 + l] * Wp[(j - c0) * Dsz + l];
#pragma unroll
        for (int m = 32; m >= 1; m >>= 1) p += __shfl_xor(p, m);
        if (l == 0) wu[j] = p;
    }
    __syncthreads();

    // ---- P6: per-group softmax -> logits; CE -> atomic loss ----
    if (w == 0) {
        float lossb = 0.f;
        if (l < NK) {
            const int LEN[5] = {2, 4, 4, 2, 6};
            const int C0[5]  = {0, 2, 6, 10, 12};
            const int gidx = l, c0 = C0[gidx], len = LEN[gidx];
            float* op = out_logit + (size_t)b * 18;
            const float* yp = y + (size_t)b * 18;
            float mx = -1e30f;
            for (int j = 0; j < len; ++j) mx = fmaxf(mx, wu[c0 + j]);
            float sum = 0.f;
            for (int j = 0; j < len; ++j) sum += __expf(wu[c0 + j] - mx);
            float inv = 1.0f / sum;
            float lse = mx + __logf(sum);
            for (int j = 0; j < len; ++j) {
                op[c0 + j] = __expf(wu[c0 + j] - mx) * inv;
                lossb += (lse - wu[c0 + j]) * yp[c0 + j];
            }
        }
#pragma unroll
        for (int m = 1; m <= 4; m <<= 1) lossb += __shfl_xor(lossb, m);
        if (l == 0) atomicAdd(loss_out, lossb * (1.0f / Bsz));
    }
}

extern "C" void kernel_launch(void* const* d_in, const int* in_sizes, int n_in,
                              void* d_out, int out_size, void* d_ws, size_t ws_size,
                              hipStream_t stream) {
    const int*   x   = (const int*)d_in[0];
    const float* y   = (const float*)d_in[1];
    const float* emb = (const float*)d_in[2];
    const float* aw  = (const float*)d_in[3];
    const float* ab  = (const float*)d_in[4];
    const float* W0  = (const float*)d_in[5];
    const float* W1  = (const float*)d_in[6];
    const float* W2  = (const float*)d_in[7];
    const float* W3  = (const float*)d_in[8];
    const float* W4  = (const float*)d_in[9];
    float* out  = (float*)d_out;
    float* loss = out + (size_t)Bsz * 18;

    zero_loss_kernel<<<1, 64, 0, stream>>>(loss);

    const size_t need = (size_t)100000 * 64 * sizeof(half_t);   // 12.8 MB
    if (d_ws && ws_size >= need) {
        half_t* tab16 = (half_t*)d_ws;
        cvt_kernel<<<(800000 + 255) / 256, 256, 0, stream>>>(emb, tab16);
        tan_kernel<true><<<Bsz, NT, 0, stream>>>(x, y, emb, tab16, aw, ab,
                                                 W0, W1, W2, W3, W4, out, loss);
    } else {
        tan_kernel<false><<<Bsz, NT, 0, stream>>>(x, y, emb, nullptr, aw, ab,
                                                  W0, W1, W2, W3, W4, out, loss);
    }
}